// Round 1
// baseline (7754.161 us; speedup 1.0000x reference)
//
#include <hip/hip_runtime.h>
#include <math.h>

typedef unsigned short u16;
typedef __attribute__((ext_vector_type(8))) short short8;   // 8 bf16 = 4 VGPRs (A/B frag)
typedef __attribute__((ext_vector_type(4))) float f32x4;    // C/D frag

static __device__ __forceinline__ u16 f2bf(float f) {
  union { float f; unsigned int u; } v; v.f = f;
  unsigned int u = v.u;
  u = u + 0x7fffu + ((u >> 16) & 1u);   // round-to-nearest-even
  return (u16)(u >> 16);
}

// block-wide sum of (s1, s2) over 256 threads; result broadcast to all
static __device__ __forceinline__ void block_reduce2(float& s1, float& s2, float* sh) {
#pragma unroll
  for (int off = 32; off > 0; off >>= 1) {
    s1 += __shfl_xor(s1, off);
    s2 += __shfl_xor(s2, off);
  }
  int tid = threadIdx.x, wv = tid >> 6, lane = tid & 63;
  if (lane == 0) { sh[wv] = s1; sh[4 + wv] = s2; }
  __syncthreads();
  s1 = sh[0] + sh[1] + sh[2] + sh[3];
  s2 = sh[4] + sh[5] + sh[6] + sh[7];
}

// ---------------------------------------------------------------------------
// Kernel 1: gaussian smooth (depthwise conv k=20, pads 9/10) + patchify +
// LayerNorm(patch_ln1) -> bf16 rows (2048 x 1024). row = b*512+n, col = tt*256+f
// ---------------------------------------------------------------------------
__global__ __launch_bounds__(256) void smooth_patch_ln(
    const float* __restrict__ in, const float* __restrict__ g,
    const float* __restrict__ b, u16* __restrict__ out) {
  __shared__ float sh[8];
  int row = blockIdx.x;
  int bb = row >> 9, n = row & 511;
  int f = threadIdx.x;
  float gk[20]; float gs = 0.f;
#pragma unroll
  for (int k = 0; k < 20; ++k) {
    float d = ((float)k - 9.5f) * 0.5f;   // (k - mean)/sigma, sigma=2
    gk[k] = __expf(-0.5f * d * d);
    gs += gk[k];
  }
  float inv = 1.f / gs;                    // normalization; 1/(sigma*sqrt(2pi)) cancels
  const float* base = in + (size_t)bb * 2048 * 256 + f;
  float vals[4]; float s1 = 0.f, s2 = 0.f;
#pragma unroll
  for (int tt = 0; tt < 4; ++tt) {
    int t = n * 4 + tt;
    float a = 0.f;
#pragma unroll
    for (int k = 0; k < 20; ++k) {
      int ts = t + k - 9;                 // cross-correlation, pad (9,10)
      if (ts >= 0 && ts < 2048) a += gk[k] * base[(size_t)ts * 256];
    }
    a *= inv;
    vals[tt] = a; s1 += a; s2 += a * a;
  }
  block_reduce2(s1, s2, sh);
  float mean = s1 * (1.f / 1024.f);
  float var = s2 * (1.f / 1024.f) - mean * mean;
  float rstd = rsqrtf(var + 1e-5f);
#pragma unroll
  for (int tt = 0; tt < 4; ++tt) {
    int idx = tt * 256 + f;
    float o = (vals[tt] - mean) * rstd * g[idx] + b[idx];
    out[(size_t)row * 1024 + idx] = f2bf(o);
  }
}

// ---------------------------------------------------------------------------
// LayerNorm over 1024 cols. OBF16: write bf16 (GEMM input) else fp32 (stream).
// Safe in-place for fp32 (each thread rewrites only what it read).
// ---------------------------------------------------------------------------
template <bool OBF16>
__global__ __launch_bounds__(256) void ln_kernel(
    const float* __restrict__ x, const float* __restrict__ g,
    const float* __restrict__ b, void* __restrict__ outp) {
  __shared__ float sh[8];
  int row = blockIdx.x, tid = threadIdx.x;
  float4 v = ((const float4*)(x + (size_t)row * 1024))[tid];
  float s1 = v.x + v.y + v.z + v.w;
  float s2 = v.x * v.x + v.y * v.y + v.z * v.z + v.w * v.w;
  block_reduce2(s1, s2, sh);
  float mean = s1 * (1.f / 1024.f);
  float var = s2 * (1.f / 1024.f) - mean * mean;
  float rstd = rsqrtf(var + 1e-5f);
  float4 gv = ((const float4*)g)[tid];
  float4 bv = ((const float4*)b)[tid];
  float o0 = (v.x - mean) * rstd * gv.x + bv.x;
  float o1 = (v.y - mean) * rstd * gv.y + bv.y;
  float o2 = (v.z - mean) * rstd * gv.z + bv.z;
  float o3 = (v.w - mean) * rstd * gv.w + bv.w;
  if (OBF16) {
    ushort4 h; h.x = f2bf(o0); h.y = f2bf(o1); h.z = f2bf(o2); h.w = f2bf(o3);
    ((ushort4*)outp)[(size_t)row * 256 + tid] = h;
  } else {
    float4 o; o.x = o0; o.y = o1; o.z = o2; o.w = o3;
    ((float4*)outp)[(size_t)row * 256 + tid] = o;
  }
}

// ---------------------------------------------------------------------------
// GEMM: C[M,N] = A[M,K](bf16) @ W[N,K](fp32, cvt->bf16 in staging)^T
// 128x128 block tile, BK=32, 4 waves in 2x2, wave tile 64x64 = 4x4 MFMAs.
// EPI: 0 bias->f32 | 1 (no bias)->bf16 | 2 bias+residual->f32 | 3 bias+GELU->bf16
// M multiple of 128; N arbitrary (guarded); K multiple of 32.
// ---------------------------------------------------------------------------
template <int EPI>
__global__ __launch_bounds__(256) void gemm_kernel(
    const u16* __restrict__ A, const float* __restrict__ W,
    const float* __restrict__ bias, const float* __restrict__ res,
    void* __restrict__ outp, int M, int N, int K) {
  __shared__ u16 As[128 * 32];   // [row][k], 64B rows
  __shared__ u16 Bs[128 * 32];   // [n][k]
  int tid = threadIdx.x;
  int lane = tid & 63, wv = tid >> 6;
  int quad = lane >> 4, l16 = lane & 15;
  int wm = wv >> 1, wn = wv & 1;
  int m0 = blockIdx.x * 128, n0 = blockIdx.y * 128;
  f32x4 acc[4][4] = {};

  for (int k0 = 0; k0 < K; k0 += 32) {
    __syncthreads();
    // stage A: 512 x 16B chunks
#pragma unroll
    for (int i = 0; i < 2; ++i) {
      int ci = tid + i * 256;
      int row = ci >> 2, ko = (ci & 3) * 8;
      *reinterpret_cast<uint4*>(&As[row * 32 + ko]) =
          *reinterpret_cast<const uint4*>(A + (size_t)(m0 + row) * K + k0 + ko);
    }
    // stage B: fp32 -> bf16, 1024 x 4-float chunks, guard n<N
#pragma unroll
    for (int i = 0; i < 4; ++i) {
      int ci = tid + i * 256;
      int row = ci >> 3, ko = (ci & 7) * 4;
      int gn = n0 + row;
      float4 w4 = make_float4(0.f, 0.f, 0.f, 0.f);
      if (gn < N) w4 = *reinterpret_cast<const float4*>(W + (size_t)gn * K + k0 + ko);
      ushort4 h; h.x = f2bf(w4.x); h.y = f2bf(w4.y); h.z = f2bf(w4.z); h.w = f2bf(w4.w);
      *reinterpret_cast<ushort4*>(&Bs[row * 32 + ko]) = h;
    }
    __syncthreads();
    short8 af[4], bfr[4];
#pragma unroll
    for (int mt = 0; mt < 4; ++mt)
      af[mt] = *reinterpret_cast<const short8*>(&As[(wm * 64 + mt * 16 + l16) * 32 + quad * 8]);
#pragma unroll
    for (int nt = 0; nt < 4; ++nt)
      bfr[nt] = *reinterpret_cast<const short8*>(&Bs[(wn * 64 + nt * 16 + l16) * 32 + quad * 8]);
#pragma unroll
    for (int mt = 0; mt < 4; ++mt)
#pragma unroll
      for (int nt = 0; nt < 4; ++nt)
        acc[mt][nt] = __builtin_amdgcn_mfma_f32_16x16x32_bf16(af[mt], bfr[nt], acc[mt][nt], 0, 0, 0);
  }

  float* outf = (float*)outp;
  u16* outh = (u16*)outp;
#pragma unroll
  for (int nt = 0; nt < 4; ++nt) {
    int col = n0 + wn * 64 + nt * 16 + l16;
    if (col >= N) continue;
    float bv = (EPI == 1) ? 0.f : bias[col];
#pragma unroll
    for (int mt = 0; mt < 4; ++mt) {
      int rowb = m0 + wm * 64 + mt * 16 + quad * 4;
#pragma unroll
      for (int r = 0; r < 4; ++r) {
        size_t idx = (size_t)(rowb + r) * N + col;
        float v = acc[mt][nt][r] + bv;
        if (EPI == 0) outf[idx] = v;
        else if (EPI == 1) outh[idx] = f2bf(v);
        else if (EPI == 2) outf[idx] = v + res[idx];
        else outh[idx] = f2bf(0.5f * v * (1.f + erff(v * 0.70710678118f)));
      }
    }
  }
}

// ---------------------------------------------------------------------------
// Fused causal attention with relative-position bias, flash-style.
// grid (8 q-tiles, 64 b*h). block 256 = 4 waves; wave handles 16 q rows.
// qkv: (2048, 3072) bf16 rows = [q | k | v] each (h,dh). o: (2048, 1024) bf16.
// ---------------------------------------------------------------------------
__global__ __launch_bounds__(256) void attn_kernel(
    const u16* __restrict__ qkv, const float* __restrict__ rel,
    u16* __restrict__ o) {
  __shared__ u16 Ks[64 * 64];     // [key][dh]
  __shared__ u16 Vt[64 * 64];     // [dh][key] (transposed for B-frag reads)
  __shared__ u16 Ps[4][16 * 64];  // per-wave P tile [m][key]
  __shared__ float rel_s[399];
  int tid = threadIdx.x;
  int qt = blockIdx.x, bh = blockIdx.y;
  int bb = bh >> 4, h = bh & 15;
  for (int i = tid; i < 399; i += 256) rel_s[i] = rel[i];
  int wv = tid >> 6, lane = tid & 63, quad = lane >> 4, l16 = lane & 15;

  // Q fragments stay in registers (A-layout: m=l16, k=quad*8+j)
  int qrow = qt * 64 + wv * 16 + l16;
  const u16* qptr = qkv + ((size_t)(bb * 512 + qrow) * 3072 + h * 64 + quad * 8);
  short8 aq0 = *reinterpret_cast<const short8*>(qptr);
  short8 aq1 = *reinterpret_cast<const short8*>(qptr + 32);

  f32x4 od[4] = {};
  float m_i[4], l_i[4], alpha[4];
#pragma unroll
  for (int r = 0; r < 4; ++r) { m_i[r] = -1e30f; l_i[r] = 0.f; }

  for (int kt = 0; kt <= qt; ++kt) {
    __syncthreads();
    // stage K (straight) and V (transposed)
#pragma unroll
    for (int i = 0; i < 2; ++i) {
      int ci = tid + i * 256;
      int krow = ci >> 3, ch = ci & 7;
      const u16* kp = qkv + ((size_t)(bb * 512 + kt * 64 + krow) * 3072 + 1024 + h * 64 + ch * 8);
      *reinterpret_cast<uint4*>(&Ks[krow * 64 + ch * 8]) = *reinterpret_cast<const uint4*>(kp);
      u16 vvv[8];
      *reinterpret_cast<uint4*>(vvv) = *reinterpret_cast<const uint4*>(kp + 1024);
#pragma unroll
      for (int jj = 0; jj < 8; ++jj) Vt[(ch * 8 + jj) * 64 + krow] = vvv[jj];
    }
    __syncthreads();
    // S = Q K^T  (16 x 64 per wave)
    f32x4 s[4];
#pragma unroll
    for (int nt = 0; nt < 4; ++nt) {
      f32x4 z = {};
      short8 b0 = *reinterpret_cast<const short8*>(&Ks[(nt * 16 + l16) * 64 + quad * 8]);
      short8 b1 = *reinterpret_cast<const short8*>(&Ks[(nt * 16 + l16) * 64 + 32 + quad * 8]);
      z = __builtin_amdgcn_mfma_f32_16x16x32_bf16(aq0, b0, z, 0, 0, 0);
      z = __builtin_amdgcn_mfma_f32_16x16x32_bf16(aq1, b1, z, 0, 0, 0);
      s[nt] = z;
    }
    // scale + relative bias + causal mask (C-layout: row=quad*4+r, col=l16)
    int ibase = qt * 64 + wv * 16 + quad * 4;
#pragma unroll
    for (int nt = 0; nt < 4; ++nt) {
      int j = kt * 64 + nt * 16 + l16;
#pragma unroll
      for (int r = 0; r < 4; ++r) {
        int d = ibase + r - j;
        float v = s[nt][r] * 0.125f;
        v = (d >= 0) ? v + rel_s[(d > 199 ? 199 : d) + 199] : -1e30f;
        s[nt][r] = v;
      }
    }
    // online softmax per row r (reduce across the 16 lanes of the quad)
#pragma unroll
    for (int r = 0; r < 4; ++r) {
      float mx = fmaxf(fmaxf(s[0][r], s[1][r]), fmaxf(s[2][r], s[3][r]));
#pragma unroll
      for (int off = 1; off < 16; off <<= 1) mx = fmaxf(mx, __shfl_xor(mx, off));
      float mn = fmaxf(m_i[r], mx);
      alpha[r] = __expf(m_i[r] - mn);
      m_i[r] = mn;
      float rs = 0.f;
#pragma unroll
      for (int nt = 0; nt < 4; ++nt) { float p = __expf(s[nt][r] - mn); s[nt][r] = p; rs += p; }
#pragma unroll
      for (int off = 1; off < 16; off <<= 1) rs += __shfl_xor(rs, off);
      l_i[r] = l_i[r] * alpha[r] + rs;
    }
    // P (C-layout) -> LDS -> A-layout for P@V
#pragma unroll
    for (int nt = 0; nt < 4; ++nt)
#pragma unroll
      for (int r = 0; r < 4; ++r)
        Ps[wv][(quad * 4 + r) * 64 + nt * 16 + l16] = f2bf(s[nt][r]);
#pragma unroll
    for (int t = 0; t < 4; ++t)
#pragma unroll
      for (int r = 0; r < 4; ++r) od[t][r] *= alpha[r];
    __syncthreads();   // uniform trip count (qt is block-uniform) -> safe
    // O += P @ V
#pragma unroll
    for (int t = 0; t < 4; ++t) {
#pragma unroll
      for (int kf = 0; kf < 2; ++kf) {
        short8 pa = *reinterpret_cast<const short8*>(&Ps[wv][l16 * 64 + kf * 32 + quad * 8]);
        short8 vb = *reinterpret_cast<const short8*>(&Vt[(t * 16 + l16) * 64 + kf * 32 + quad * 8]);
        od[t] = __builtin_amdgcn_mfma_f32_16x16x32_bf16(pa, vb, od[t], 0, 0, 0);
      }
    }
  }
  // normalize and store (o layout matches out-proj A operand: col = h*64+dh)
#pragma unroll
  for (int t = 0; t < 4; ++t) {
#pragma unroll
    for (int r = 0; r < 4; ++r) {
      int row = qt * 64 + wv * 16 + quad * 4 + r;
      float v = od[t][r] / l_i[r];
      o[(size_t)(bb * 512 + row) * 1024 + h * 64 + t * 16 + l16] = f2bf(v);
    }
  }
}

// ---------------------------------------------------------------------------
extern "C" void kernel_launch(void* const* d_in, const int* in_sizes, int n_in,
                              void* d_out, int out_size, void* d_ws, size_t ws_size,
                              hipStream_t stream) {
  const float* neuralInput = (const float*)d_in[0];
  const float* p_ln1_g = (const float*)d_in[1];
  const float* p_ln1_b = (const float*)d_in[2];
  const float* patch_w = (const float*)d_in[3];
  const float* patch_b = (const float*)d_in[4];
  const float* p_ln2_g = (const float*)d_in[5];
  const float* p_ln2_b = (const float*)d_in[6];
  const float* attn_ln_g = (const float*)d_in[7];
  const float* attn_ln_b = (const float*)d_in[8];
  const float* qkv_w = (const float*)d_in[9];
  const float* out_w = (const float*)d_in[10];
  const float* out_b = (const float*)d_in[11];
  const float* rel_tab = (const float*)d_in[12];
  const float* ffn_ln_g = (const float*)d_in[13];
  const float* ffn_ln_b = (const float*)d_in[14];
  const float* ffn_w1 = (const float*)d_in[15];
  const float* ffn_b1 = (const float*)d_in[16];
  const float* ffn_w2 = (const float*)d_in[17];
  const float* ffn_b2 = (const float*)d_in[18];
  const float* fin_g = (const float*)d_in[19];
  const float* fin_b = (const float*)d_in[20];
  const float* proj_w = (const float*)d_in[21];
  const float* proj_b = (const float*)d_in[22];

  // workspace layout (28 MB): G aliases QKV+O (dead by the time G is written)
  char* ws = (char*)d_ws;
  u16* H = (u16*)(ws);                    // 2048x1024 bf16  [0,4M)
  float* X = (float*)(ws + (4u << 20));   // 2048x1024 fp32  [4M,12M)
  u16* QKV = (u16*)(ws + (12u << 20));    // 2048x3072 bf16  [12M,24M)
  u16* O = (u16*)(ws + (24u << 20));      // 2048x1024 bf16  [24M,28M)
  u16* G = (u16*)(ws + (12u << 20));      // 2048x4096 bf16  [12M,28M) alias

  dim3 blk(256);
  smooth_patch_ln<<<2048, blk, 0, stream>>>(neuralInput, p_ln1_g, p_ln1_b, H);
  gemm_kernel<0><<<dim3(16, 8), blk, 0, stream>>>(H, patch_w, patch_b, nullptr, X, 2048, 1024, 1024);
  ln_kernel<false><<<2048, blk, 0, stream>>>(X, p_ln2_g, p_ln2_b, X);

  for (int l = 0; l < 12; ++l) {
    ln_kernel<true><<<2048, blk, 0, stream>>>(X, attn_ln_g + l * 1024, attn_ln_b + l * 1024, H);
    gemm_kernel<1><<<dim3(16, 24), blk, 0, stream>>>(H, qkv_w + (size_t)l * 3072 * 1024, nullptr, nullptr, QKV, 2048, 3072, 1024);
    attn_kernel<<<dim3(8, 64), blk, 0, stream>>>(QKV, rel_tab + l * 399, O);
    gemm_kernel<2><<<dim3(16, 8), blk, 0, stream>>>(O, out_w + (size_t)l * 1024 * 1024, out_b + l * 1024, X, X, 2048, 1024, 1024);
    ln_kernel<true><<<2048, blk, 0, stream>>>(X, ffn_ln_g + l * 1024, ffn_ln_b + l * 1024, H);
    gemm_kernel<3><<<dim3(16, 32), blk, 0, stream>>>(H, ffn_w1 + (size_t)l * 4096 * 1024, ffn_b1 + l * 4096, nullptr, G, 2048, 4096, 1024);
    gemm_kernel<2><<<dim3(16, 8), blk, 0, stream>>>(G, ffn_w2 + (size_t)l * 1024 * 4096, ffn_b2 + l * 1024, X, X, 2048, 1024, 4096);
  }

  ln_kernel<true><<<2048, blk, 0, stream>>>(X, fin_g, fin_b, H);
  gemm_kernel<0><<<dim3(16, 1), blk, 0, stream>>>(H, proj_w, proj_b, nullptr, (float*)d_out, 2048, 41, 1024);
}

// Round 2
// 3157.735 us; speedup vs baseline: 2.4556x; 2.4556x over previous
//
#include <hip/hip_runtime.h>
#include <math.h>

typedef unsigned short u16;
typedef __attribute__((ext_vector_type(8))) short short8;   // 8 bf16 (4 VGPRs)
typedef __attribute__((ext_vector_type(4))) float f32x4;    // MFMA C/D frag

static __device__ __forceinline__ u16 f2bf(float f) {
  union { float f; unsigned int u; } v; v.f = f;
  unsigned int u = v.u;
  u = u + 0x7fffu + ((u >> 16) & 1u);   // round-to-nearest-even
  return (u16)(u >> 16);
}

// async global->LDS, 16 B per lane. LDS dest = wave-uniform base + lane*16.
typedef __attribute__((address_space(3))) void* lds_as_t;
typedef const __attribute__((address_space(1))) void* gbl_as_t;
static __device__ __forceinline__ void gload_lds16(const void* g, void* l) {
  __builtin_amdgcn_global_load_lds((gbl_as_t)g, (lds_as_t)l, 16, 0, 0);
}

static __device__ __forceinline__ void block_reduce2(float& s1, float& s2, float* sh) {
#pragma unroll
  for (int off = 32; off > 0; off >>= 1) {
    s1 += __shfl_xor(s1, off);
    s2 += __shfl_xor(s2, off);
  }
  int tid = threadIdx.x, wv = tid >> 6, lane = tid & 63;
  if (lane == 0) { sh[wv] = s1; sh[4 + wv] = s2; }
  __syncthreads();
  s1 = sh[0] + sh[1] + sh[2] + sh[3];
  s2 = sh[4] + sh[5] + sh[6] + sh[7];
}

// fp32 -> bf16 weight pre-conversion
__global__ __launch_bounds__(256) void cvt_bf16_k(const float* __restrict__ in,
                                                  u16* __restrict__ out, int n4) {
  int i = blockIdx.x * 256 + threadIdx.x;
  if (i >= n4) return;
  float4 v = ((const float4*)in)[i];
  ushort4 h; h.x = f2bf(v.x); h.y = f2bf(v.y); h.z = f2bf(v.z); h.w = f2bf(v.w);
  ((ushort4*)out)[i] = h;
}
__global__ __launch_bounds__(256) void cvt_pad_k(const float* __restrict__ in,
                                                 u16* __restrict__ out, int n4src, int n4tot) {
  int i = blockIdx.x * 256 + threadIdx.x;
  if (i >= n4tot) return;
  ushort4 h; h.x = 0; h.y = 0; h.z = 0; h.w = 0;
  if (i < n4src) {
    float4 v = ((const float4*)in)[i];
    h.x = f2bf(v.x); h.y = f2bf(v.y); h.z = f2bf(v.z); h.w = f2bf(v.w);
  }
  ((ushort4*)out)[i] = h;
}

// ---------------------------------------------------------------------------
// smooth (depthwise gauss k=20, pads 9/10) + patchify + LN(patch_ln1) -> bf16
// ---------------------------------------------------------------------------
__global__ __launch_bounds__(256) void smooth_patch_ln(
    const float* __restrict__ in, const float* __restrict__ g,
    const float* __restrict__ b, u16* __restrict__ out) {
  __shared__ float sh[8];
  int row = blockIdx.x;
  int bb = row >> 9, n = row & 511;
  int f = threadIdx.x;
  float gk[20]; float gs = 0.f;
#pragma unroll
  for (int k = 0; k < 20; ++k) {
    float d = ((float)k - 9.5f) * 0.5f;
    gk[k] = __expf(-0.5f * d * d);
    gs += gk[k];
  }
  float inv = 1.f / gs;
  const float* base = in + (size_t)bb * 2048 * 256 + f;
  float vals[4]; float s1 = 0.f, s2 = 0.f;
#pragma unroll
  for (int tt = 0; tt < 4; ++tt) {
    int t = n * 4 + tt;
    float a = 0.f;
#pragma unroll
    for (int k = 0; k < 20; ++k) {
      int ts = t + k - 9;
      if (ts >= 0 && ts < 2048) a += gk[k] * base[(size_t)ts * 256];
    }
    a *= inv;
    vals[tt] = a; s1 += a; s2 += a * a;
  }
  block_reduce2(s1, s2, sh);
  float mean = s1 * (1.f / 1024.f);
  float var = s2 * (1.f / 1024.f) - mean * mean;
  float rstd = rsqrtf(var + 1e-5f);
#pragma unroll
  for (int tt = 0; tt < 4; ++tt) {
    int idx = tt * 256 + f;
    float o = (vals[tt] - mean) * rstd * g[idx] + b[idx];
    out[(size_t)row * 1024 + idx] = f2bf(o);
  }
}

// ---------------------------------------------------------------------------
// LayerNorm over 1024 cols; bf16 or fp32 output
// ---------------------------------------------------------------------------
template <bool OBF16>
__global__ __launch_bounds__(256) void ln_kernel(
    const float* __restrict__ x, const float* __restrict__ g,
    const float* __restrict__ b, void* __restrict__ outp) {
  __shared__ float sh[8];
  int row = blockIdx.x, tid = threadIdx.x;
  float4 v = ((const float4*)(x + (size_t)row * 1024))[tid];
  float s1 = v.x + v.y + v.z + v.w;
  float s2 = v.x * v.x + v.y * v.y + v.z * v.z + v.w * v.w;
  block_reduce2(s1, s2, sh);
  float mean = s1 * (1.f / 1024.f);
  float var = s2 * (1.f / 1024.f) - mean * mean;
  float rstd = rsqrtf(var + 1e-5f);
  float4 gv = ((const float4*)g)[tid];
  float4 bv = ((const float4*)b)[tid];
  float o0 = (v.x - mean) * rstd * gv.x + bv.x;
  float o1 = (v.y - mean) * rstd * gv.y + bv.y;
  float o2 = (v.z - mean) * rstd * gv.z + bv.z;
  float o3 = (v.w - mean) * rstd * gv.w + bv.w;
  if (OBF16) {
    ushort4 h; h.x = f2bf(o0); h.y = f2bf(o1); h.z = f2bf(o2); h.w = f2bf(o3);
    ((ushort4*)outp)[(size_t)row * 256 + tid] = h;
  } else {
    float4 o; o.x = o0; o.y = o1; o.z = o2; o.w = o3;
    ((float4*)outp)[(size_t)row * 256 + tid] = o;
  }
}

// ---------------------------------------------------------------------------
// GEMM: C[M,N] = A[M,K](bf16) @ W[N,K]^T.  BM x 128 tile, BK=32.
// 4 waves 2x2; wave tile (BM/2)x64 -> MT x 4 MFMAs of 16x16x32.
// LDS layout: 16-row groups stored [chunk][row] (=global_load_lds lane order);
// fragment ds_read_b128 from consecutive lanes is contiguous -> no conflicts.
// BF16B: W already bf16, staged async. else: fp32 W inline-converted.
// EPI: 0 bias->f32 | 1 none->bf16 | 2 bias+res->f32 | 3 bias+GELU->bf16
//      4 partial->f32 at outp + z*M*N (no bias)
// grid.z = split-K; Ksplit = K-range per z.
// ---------------------------------------------------------------------------
template <int EPI, int BM, bool BF16B>
__global__ __launch_bounds__(256) void gemm_kernel(
    const u16* __restrict__ A, const void* __restrict__ Wp,
    const float* __restrict__ bias, const float* __restrict__ res,
    void* __restrict__ outp, int M, int N, int K, int Ksplit) {
  constexpr int MT = BM / 32;
  __shared__ u16 As[BM * 32];
  __shared__ u16 Bs[128 * 32];
  int tid = threadIdx.x;
  int lane = tid & 63, wv = tid >> 6;
  int quad = lane >> 4, l16 = lane & 15;
  int wm = wv >> 1, wn = wv & 1;
  int m0 = blockIdx.x * BM, n0 = blockIdx.y * 128;
  int z = blockIdx.z;
  int kbeg = z * Ksplit, kend = kbeg + Ksplit;
  int sr = lane & 15, sc = lane >> 4;     // staging: lane -> (row, chunk)
  const u16* Wb = (const u16*)Wp;
  const float* Wf = (const float*)Wp;
  f32x4 acc[MT][4] = {};

  for (int k0 = kbeg; k0 < kend; k0 += 32) {
    __syncthreads();
    // A tile: BM/16 groups of 1 KB, one wave-load each
#pragma unroll
    for (int i = 0; i < BM / 64; ++i) {
      int g = wv + 4 * i;
      gload_lds16(A + (size_t)(m0 + g * 16 + sr) * K + k0 + sc * 8, &As[g * 512]);
    }
    if constexpr (BF16B) {
#pragma unroll
      for (int i = 0; i < 2; ++i) {
        int g = wv + 4 * i;
        gload_lds16(Wb + (size_t)(n0 + g * 16 + sr) * K + k0 + sc * 8, &Bs[g * 512]);
      }
    } else {
#pragma unroll
      for (int it = 0; it < 2; ++it) {
        int cid = it * 256 + tid;            // 512 chunks of 16 B
        int g = cid >> 6, rem = cid & 63, c = rem >> 4, r = rem & 15;
        int gn = n0 + g * 16 + r;
        float4 wa = make_float4(0.f, 0.f, 0.f, 0.f), wb = wa;
        if (gn < N) {
          const float* wp = Wf + (size_t)gn * K + k0 + c * 8;
          wa = *(const float4*)wp; wb = *(const float4*)(wp + 4);
        }
        ushort4 h0, h1;
        h0.x = f2bf(wa.x); h0.y = f2bf(wa.y); h0.z = f2bf(wa.z); h0.w = f2bf(wa.w);
        h1.x = f2bf(wb.x); h1.y = f2bf(wb.y); h1.z = f2bf(wb.z); h1.w = f2bf(wb.w);
        *(ushort4*)&Bs[g * 512 + c * 128 + r * 8] = h0;
        *(ushort4*)&Bs[g * 512 + c * 128 + r * 8 + 4] = h1;
      }
    }
    __syncthreads();
    short8 af[MT], bf[4];
#pragma unroll
    for (int mt = 0; mt < MT; ++mt)
      af[mt] = *(const short8*)&As[(wm * MT + mt) * 512 + quad * 128 + l16 * 8];
#pragma unroll
    for (int nt = 0; nt < 4; ++nt)
      bf[nt] = *(const short8*)&Bs[(wn * 4 + nt) * 512 + quad * 128 + l16 * 8];
#pragma unroll
    for (int mt = 0; mt < MT; ++mt)
#pragma unroll
      for (int nt = 0; nt < 4; ++nt)
        acc[mt][nt] = __builtin_amdgcn_mfma_f32_16x16x32_bf16(af[mt], bf[nt], acc[mt][nt], 0, 0, 0);
  }

  float* outf = (float*)outp;
  u16* outh = (u16*)outp;
  size_t zoff = (size_t)z * M * N;
#pragma unroll
  for (int nt = 0; nt < 4; ++nt) {
    int col = n0 + wn * 64 + nt * 16 + l16;
    if (col >= N) continue;
    float bv = (EPI == 1 || EPI == 4) ? 0.f : bias[col];
#pragma unroll
    for (int mt = 0; mt < MT; ++mt) {
      int rowb = m0 + wm * (BM / 2) + mt * 16 + quad * 4;
#pragma unroll
      for (int r = 0; r < 4; ++r) {
        size_t idx = (size_t)(rowb + r) * N + col;
        float v = acc[mt][nt][r] + bv;
        if (EPI == 0) outf[idx] = v;
        else if (EPI == 1) outh[idx] = f2bf(v);
        else if (EPI == 2) outf[idx] = v + res[idx];
        else if (EPI == 3) outh[idx] = f2bf(0.5f * v * (1.f + erff(v * 0.70710678118f)));
        else outf[zoff + idx] = v;
      }
    }
  }
}

// split-K reduce (N=1024 paths): out = sum_z P[z] + bias (+res). float4 lanes.
template <bool RES>
__global__ __launch_bounds__(256) void reduce4_k(
    const float* __restrict__ P, const float* __restrict__ bias,
    const float* __restrict__ res, float* __restrict__ out,
    int MN, int NS) {
  int i = blockIdx.x * 256 + threadIdx.x;
  int e = i * 4;
  if (e >= MN) return;
  float4 s = ((const float4*)P)[i];
  for (int z = 1; z < NS; ++z) {
    float4 p = *(const float4*)(P + (size_t)z * MN + e);
    s.x += p.x; s.y += p.y; s.z += p.z; s.w += p.w;
  }
  int col = e & 1023;
  float4 b4 = *(const float4*)(bias + col);
  s.x += b4.x; s.y += b4.y; s.z += b4.z; s.w += b4.w;
  if (RES) {
    float4 r4 = ((const float4*)res)[i];
    s.x += r4.x; s.y += r4.y; s.z += r4.z; s.w += r4.w;
  }
  ((float4*)out)[i] = s;
}

// proj reduce: N=41, scalar
__global__ __launch_bounds__(64) void reduce_proj_k(
    const float* __restrict__ P, const float* __restrict__ bias,
    float* __restrict__ out, int NS) {
  int row = blockIdx.x, col = threadIdx.x;
  if (col >= 41) return;
  float s = 0.f;
  for (int z = 0; z < NS; ++z) s += P[(size_t)z * 2048 * 41 + row * 41 + col];
  out[row * 41 + col] = s + bias[col];
}

// ---------------------------------------------------------------------------
// flash-style causal attention + relative bias (unchanged from round 1)
// ---------------------------------------------------------------------------
__global__ __launch_bounds__(256) void attn_kernel(
    const u16* __restrict__ qkv, const float* __restrict__ rel,
    u16* __restrict__ o) {
  __shared__ u16 Ks[64 * 64];
  __shared__ u16 Vt[64 * 64];
  __shared__ u16 Ps[4][16 * 64];
  __shared__ float rel_s[399];
  int tid = threadIdx.x;
  int qt = blockIdx.x, bh = blockIdx.y;
  int bb = bh >> 4, h = bh & 15;
  for (int i = tid; i < 399; i += 256) rel_s[i] = rel[i];
  int wv = tid >> 6, lane = tid & 63, quad = lane >> 4, l16 = lane & 15;

  int qrow = qt * 64 + wv * 16 + l16;
  const u16* qptr = qkv + ((size_t)(bb * 512 + qrow) * 3072 + h * 64 + quad * 8);
  short8 aq0 = *reinterpret_cast<const short8*>(qptr);
  short8 aq1 = *reinterpret_cast<const short8*>(qptr + 32);

  f32x4 od[4] = {};
  float m_i[4], l_i[4], alpha[4];
#pragma unroll
  for (int r = 0; r < 4; ++r) { m_i[r] = -1e30f; l_i[r] = 0.f; }

  for (int kt = 0; kt <= qt; ++kt) {
    __syncthreads();
#pragma unroll
    for (int i = 0; i < 2; ++i) {
      int ci = tid + i * 256;
      int krow = ci >> 3, ch = ci & 7;
      const u16* kp = qkv + ((size_t)(bb * 512 + kt * 64 + krow) * 3072 + 1024 + h * 64 + ch * 8);
      *reinterpret_cast<uint4*>(&Ks[krow * 64 + ch * 8]) = *reinterpret_cast<const uint4*>(kp);
      u16 vvv[8];
      *reinterpret_cast<uint4*>(vvv) = *reinterpret_cast<const uint4*>(kp + 1024);
#pragma unroll
      for (int jj = 0; jj < 8; ++jj) Vt[(ch * 8 + jj) * 64 + krow] = vvv[jj];
    }
    __syncthreads();
    f32x4 s[4];
#pragma unroll
    for (int nt = 0; nt < 4; ++nt) {
      f32x4 zacc = {};
      short8 b0 = *reinterpret_cast<const short8*>(&Ks[(nt * 16 + l16) * 64 + quad * 8]);
      short8 b1 = *reinterpret_cast<const short8*>(&Ks[(nt * 16 + l16) * 64 + 32 + quad * 8]);
      zacc = __builtin_amdgcn_mfma_f32_16x16x32_bf16(aq0, b0, zacc, 0, 0, 0);
      zacc = __builtin_amdgcn_mfma_f32_16x16x32_bf16(aq1, b1, zacc, 0, 0, 0);
      s[nt] = zacc;
    }
    int ibase = qt * 64 + wv * 16 + quad * 4;
#pragma unroll
    for (int nt = 0; nt < 4; ++nt) {
      int j = kt * 64 + nt * 16 + l16;
#pragma unroll
      for (int r = 0; r < 4; ++r) {
        int d = ibase + r - j;
        float v = s[nt][r] * 0.125f;
        v = (d >= 0) ? v + rel_s[(d > 199 ? 199 : d) + 199] : -1e30f;
        s[nt][r] = v;
      }
    }
#pragma unroll
    for (int r = 0; r < 4; ++r) {
      float mx = fmaxf(fmaxf(s[0][r], s[1][r]), fmaxf(s[2][r], s[3][r]));
#pragma unroll
      for (int off = 1; off < 16; off <<= 1) mx = fmaxf(mx, __shfl_xor(mx, off));
      float mn = fmaxf(m_i[r], mx);
      alpha[r] = __expf(m_i[r] - mn);
      m_i[r] = mn;
      float rs = 0.f;
#pragma unroll
      for (int nt = 0; nt < 4; ++nt) { float p = __expf(s[nt][r] - mn); s[nt][r] = p; rs += p; }
#pragma unroll
      for (int off = 1; off < 16; off <<= 1) rs += __shfl_xor(rs, off);
      l_i[r] = l_i[r] * alpha[r] + rs;
    }
#pragma unroll
    for (int nt = 0; nt < 4; ++nt)
#pragma unroll
      for (int r = 0; r < 4; ++r)
        Ps[wv][(quad * 4 + r) * 64 + nt * 16 + l16] = f2bf(s[nt][r]);
#pragma unroll
    for (int t = 0; t < 4; ++t)
#pragma unroll
      for (int r = 0; r < 4; ++r) od[t][r] *= alpha[r];
    __syncthreads();
#pragma unroll
    for (int t = 0; t < 4; ++t) {
#pragma unroll
      for (int kf = 0; kf < 2; ++kf) {
        short8 pa = *reinterpret_cast<const short8*>(&Ps[wv][l16 * 64 + kf * 32 + quad * 8]);
        short8 vb = *reinterpret_cast<const short8*>(&Vt[(t * 16 + l16) * 64 + kf * 32 + quad * 8]);
        od[t] = __builtin_amdgcn_mfma_f32_16x16x32_bf16(pa, vb, od[t], 0, 0, 0);
      }
    }
  }
#pragma unroll
  for (int t = 0; t < 4; ++t) {
#pragma unroll
    for (int r = 0; r < 4; ++r) {
      int row = qt * 64 + wv * 16 + quad * 4 + r;
      float v = od[t][r] / l_i[r];
      o[(size_t)(bb * 512 + row) * 1024 + h * 64 + t * 16 + l16] = f2bf(v);
    }
  }
}

// ---------------------------------------------------------------------------
extern "C" void kernel_launch(void* const* d_in, const int* in_sizes, int n_in,
                              void* d_out, int out_size, void* d_ws, size_t ws_size,
                              hipStream_t stream) {
  const float* neuralInput = (const float*)d_in[0];
  const float* p_ln1_g = (const float*)d_in[1];
  const float* p_ln1_b = (const float*)d_in[2];
  const float* patch_w = (const float*)d_in[3];
  const float* patch_b = (const float*)d_in[4];
  const float* p_ln2_g = (const float*)d_in[5];
  const float* p_ln2_b = (const float*)d_in[6];
  const float* attn_ln_g = (const float*)d_in[7];
  const float* attn_ln_b = (const float*)d_in[8];
  const float* qkv_w = (const float*)d_in[9];
  const float* out_w = (const float*)d_in[10];
  const float* out_b = (const float*)d_in[11];
  const float* rel_tab = (const float*)d_in[12];
  const float* ffn_ln_g = (const float*)d_in[13];
  const float* ffn_ln_b = (const float*)d_in[14];
  const float* ffn_w1 = (const float*)d_in[15];
  const float* ffn_b1 = (const float*)d_in[16];
  const float* ffn_w2 = (const float*)d_in[17];
  const float* ffn_b2 = (const float*)d_in[18];
  const float* fin_g = (const float*)d_in[19];
  const float* fin_b = (const float*)d_in[20];
  const float* proj_w = (const float*)d_in[21];
  const float* proj_b = (const float*)d_in[22];

  char* ws = (char*)d_ws;
  u16* H = (u16*)ws;                       // 2048x1024 bf16  [0,4M)
  float* X = (float*)(ws + (4ull << 20));  // 2048x1024 fp32  [4M,12M)
  u16* QKV = (u16*)(ws + (12ull << 20));   // 2048x3072 bf16  [12M,24M)
  u16* O = (u16*)(ws + (24ull << 20));     // 2048x1024 bf16  [24M,28M)

  const bool full = ws_size >= 384040960ull;   // preconverted-weights path
  dim3 blk(256);

  if (full) {
    u16* G = (u16*)(ws + (28ull << 20));       // 2048x4096 bf16 [28M,44M)
    float* P = (float*)(ws + (44ull << 20));   // split-K partials, 32M [44M,76M)
    u16* Wb = (u16*)(ws + (76ull << 20));      // bf16 weights (~290M)
    u16* qkvB = Wb;
    u16* outB = qkvB + 37748736ull;
    u16* ffn1B = outB + 12582912ull;
    u16* ffn2B = ffn1B + 50331648ull;
    u16* patchB = ffn2B + 50331648ull;
    u16* projB = patchB + 1048576ull;          // padded to 128x1024

    cvt_bf16_k<<<(9437184 + 255) / 256, blk, 0, stream>>>(qkv_w, qkvB, 9437184);
    cvt_bf16_k<<<(3145728 + 255) / 256, blk, 0, stream>>>(out_w, outB, 3145728);
    cvt_bf16_k<<<(12582912 + 255) / 256, blk, 0, stream>>>(ffn_w1, ffn1B, 12582912);
    cvt_bf16_k<<<(12582912 + 255) / 256, blk, 0, stream>>>(ffn_w2, ffn2B, 12582912);
    cvt_bf16_k<<<(262144 + 255) / 256, blk, 0, stream>>>(patch_w, patchB, 262144);
    cvt_pad_k<<<(32768 + 255) / 256, blk, 0, stream>>>(proj_w, projB, 10496, 32768);

    smooth_patch_ln<<<2048, blk, 0, stream>>>(neuralInput, p_ln1_g, p_ln1_b, H);
    gemm_kernel<4, 128, true><<<dim3(16, 8, 2), blk, 0, stream>>>(H, patchB, nullptr, nullptr, P, 2048, 1024, 1024, 512);
    reduce4_k<false><<<2048, blk, 0, stream>>>(P, patch_b, nullptr, X, 2097152, 2);
    ln_kernel<false><<<2048, blk, 0, stream>>>(X, p_ln2_g, p_ln2_b, X);

    for (int l = 0; l < 12; ++l) {
      ln_kernel<true><<<2048, blk, 0, stream>>>(X, attn_ln_g + l * 1024, attn_ln_b + l * 1024, H);
      gemm_kernel<1, 128, true><<<dim3(16, 24, 1), blk, 0, stream>>>(H, qkvB + (size_t)l * 3145728, nullptr, nullptr, QKV, 2048, 3072, 1024, 1024);
      attn_kernel<<<dim3(8, 64), blk, 0, stream>>>(QKV, rel_tab + l * 399, O);
      gemm_kernel<4, 128, true><<<dim3(16, 8, 2), blk, 0, stream>>>(O, outB + (size_t)l * 1048576, nullptr, nullptr, P, 2048, 1024, 1024, 512);
      reduce4_k<true><<<2048, blk, 0, stream>>>(P, out_b + l * 1024, X, X, 2097152, 2);
      ln_kernel<true><<<2048, blk, 0, stream>>>(X, ffn_ln_g + l * 1024, ffn_ln_b + l * 1024, H);
      gemm_kernel<3, 128, true><<<dim3(16, 32, 1), blk, 0, stream>>>(H, ffn1B + (size_t)l * 4194304, ffn_b1 + l * 4096, nullptr, G, 2048, 4096, 1024, 1024);
      gemm_kernel<4, 128, true><<<dim3(16, 8, 4), blk, 0, stream>>>(G, ffn2B + (size_t)l * 4194304, nullptr, nullptr, P, 2048, 1024, 4096, 1024);
      reduce4_k<true><<<2048, blk, 0, stream>>>(P, ffn_b2 + l * 1024, X, X, 2097152, 4);
    }

    ln_kernel<true><<<2048, blk, 0, stream>>>(X, fin_g, fin_b, H);
    gemm_kernel<4, 128, true><<<dim3(16, 1, 8), blk, 0, stream>>>(H, projB, nullptr, nullptr, P, 2048, 41, 1024, 128);
    reduce_proj_k<<<2048, 64, 0, stream>>>(P, proj_b, (float*)d_out, 8);
  } else {
    // fallback: 28 MB footprint, inline fp32->bf16 W staging, no split-K
    u16* G = (u16*)(ws + (12ull << 20));   // aliases QKV+O (dead when written)

    smooth_patch_ln<<<2048, blk, 0, stream>>>(neuralInput, p_ln1_g, p_ln1_b, H);
    gemm_kernel<0, 64, false><<<dim3(32, 8, 1), blk, 0, stream>>>(H, patch_w, patch_b, nullptr, X, 2048, 1024, 1024, 1024);
    ln_kernel<false><<<2048, blk, 0, stream>>>(X, p_ln2_g, p_ln2_b, X);

    for (int l = 0; l < 12; ++l) {
      ln_kernel<true><<<2048, blk, 0, stream>>>(X, attn_ln_g + l * 1024, attn_ln_b + l * 1024, H);
      gemm_kernel<1, 128, false><<<dim3(16, 24, 1), blk, 0, stream>>>(H, qkv_w + (size_t)l * 3145728, nullptr, nullptr, QKV, 2048, 3072, 1024, 1024);
      attn_kernel<<<dim3(8, 64), blk, 0, stream>>>(QKV, rel_tab + l * 399, O);
      gemm_kernel<2, 64, false><<<dim3(32, 8, 1), blk, 0, stream>>>(O, out_w + (size_t)l * 1048576, out_b + l * 1024, X, X, 2048, 1024, 1024, 1024);
      ln_kernel<true><<<2048, blk, 0, stream>>>(X, ffn_ln_g + l * 1024, ffn_ln_b + l * 1024, H);
      gemm_kernel<3, 128, false><<<dim3(16, 32, 1), blk, 0, stream>>>(H, ffn_w1 + (size_t)l * 4194304, ffn_b1 + l * 4096, nullptr, G, 2048, 4096, 1024, 1024);
      gemm_kernel<2, 64, false><<<dim3(32, 8, 1), blk, 0, stream>>>(G, ffn_w2 + (size_t)l * 4194304, ffn_b2 + l * 1024, X, X, 2048, 1024, 4096, 4096);
    }

    ln_kernel<true><<<2048, blk, 0, stream>>>(X, fin_g, fin_b, H);
    gemm_kernel<0, 64, false><<<dim3(32, 1, 1), blk, 0, stream>>>(H, proj_w, proj_b, nullptr, (float*)d_out, 2048, 41, 1024, 1024);
  }
}